// Round 4
// baseline (622.460 us; speedup 1.0000x reference)
//
#include <hip/hip_runtime.h>
#include <hip/hip_bf16.h>
#include <math.h>

// Problem constants
#define BB 4
#define CIN 64
#define CH 32
#define HH 64
#define WW 64
#define NN 4096           // H*W
#define MCH 4
#define NQCH 8            // q-chunks for column stats

// ws layout (floats). Total 1,229,824 floats = 4.69 MiB.
// Temporal aliasing (safe; stream-ordered):
//   CPMAX/CPSUM live only k2a->k2b.
//   RMAP/CMAPF/XA alias that region, written k3/k4 (after k2b).
#define PP_OFF     0          // 1024
#define Q4_OFF     1024       // 65536
#define K4_OFF     66560      // 65536
#define CV_OFF     132096     // 16384
#define CPMAX_OFF  148480     // 131072 (dead after k2b)
#define CPSUM_OFF  279552     // 131072 (dead after k2b)
#define RMAP_OFF   148480     // 16384  (aliases CPMAX head, written in k3)
#define CMAPF_OFF  164864     // 16384  (aliases CPMAX,   written in k3)
#define XA_OFF     181248     // 524288 (aliases CPMAX tail+CPSUM, written in k4)
#define XB_OFF     705536     // 524288 (fresh)
// end = 1229824 floats = 4,919,296 bytes

// out layout (FLOAT32 elements): x | out | corrected_map
#define OUT_X_OFF   0
#define OUT_O_OFF   524288
#define OUT_CM_OFF  540672

__device__ __forceinline__ float bilin32(const float* src, int b, int y, int x) {
    // (B,1,32,32) -> sample at 64x64 pixel (y,x); jax.image.resize bilinear:
    // half-pixel centers; boundary weight renormalization == edge clamp here.
    float sy = 0.5f * y - 0.25f;
    float sx = 0.5f * x - 0.25f;
    float fy0 = floorf(sy), fx0 = floorf(sx);
    int y0 = (int)fy0, x0 = (int)fx0;
    float fy = sy - fy0, fx = sx - fx0;
    int y0c = min(max(y0, 0), 31), y1c = min(max(y0 + 1, 0), 31);
    int x0c = min(max(x0, 0), 31), x1c = min(max(x0 + 1, 0), 31);
    const float* p = src + b * 1024;
    float v00 = p[y0c * 32 + x0c], v01 = p[y0c * 32 + x1c];
    float v10 = p[y1c * 32 + x0c], v11 = p[y1c * 32 + x1c];
    float v0 = v00 + fx * (v01 - v00);
    float v1 = v10 + fx * (v11 - v10);
    return v0 + fy * (v1 - v0);
}

// K0: pos embedding projected through wq/wk, decomposed per coordinate (exact).
__global__ void k0_posproj(const float* __restrict__ wq, const float* __restrict__ wk,
                           float* __restrict__ pp) {
    int t = threadIdx.x;  // coordinate 0..63
    float coord = (float)(t + 1);
    float qy[4] = {0,0,0,0}, qx[4] = {0,0,0,0}, ky[4] = {0,0,0,0}, kx[4] = {0,0,0,0};
    for (int c = 0; c < 32; ++c) {
        float e = (2.0f * (float)(c / 2)) / 32.0f;
        float dim = powf(10000.0f, e);
        float ang = coord / dim;
        float pr = (c & 1) ? cosf(ang) : sinf(ang);
        #pragma unroll
        for (int m = 0; m < 4; ++m) {
            qy[m] += wq[m * 64 + c] * pr;
            qx[m] += wq[m * 64 + 32 + c] * pr;
            ky[m] += wk[m * 64 + c] * pr;
            kx[m] += wk[m * 64 + 32 + c] * pr;
        }
    }
    #pragma unroll
    for (int m = 0; m < 4; ++m) {
        pp[0 * 256 + m * 64 + t] = qy[m];
        pp[1 * 256 + m * 64 + t] = qx[m];
        pp[2 * 256 + m * 64 + t] = ky[m];
        pp[3 * 256 + m * 64 + t] = kx[m];
    }
}

// K1: Q[b,hw,m], K[b,hw,m] projections
__global__ void k1_qk(const float* __restrict__ fq, const float* __restrict__ fk,
                      const float* __restrict__ wq, const float* __restrict__ wk,
                      const float* __restrict__ pp,
                      float* __restrict__ Q4, float* __restrict__ K4) {
    __shared__ float wqs[256], wks[256];
    int tid = threadIdx.x;
    wqs[tid] = wq[tid];
    wks[tid] = wk[tid];
    __syncthreads();
    int gid = blockIdx.x * 256 + tid;           // 0..B*N
    int b = gid >> 12, hw = gid & 4095;
    int y = hw >> 6, x = hw & 63;
    float aq[4], ak[4];
    #pragma unroll
    for (int m = 0; m < 4; ++m) {
        aq[m] = pp[0 * 256 + m * 64 + y] + pp[1 * 256 + m * 64 + x];
        ak[m] = pp[2 * 256 + m * 64 + y] + pp[3 * 256 + m * 64 + x];
    }
    const float* fqb = fq + b * (CIN * NN) + hw;
    const float* fkb = fk + b * (CIN * NN) + hw;
    for (int c = 0; c < 64; ++c) {
        float vq = fqb[c * NN];
        float vk = fkb[c * NN];
        #pragma unroll
        for (int m = 0; m < 4; ++m) {
            aq[m] += wqs[m * 64 + c] * vq;
            ak[m] += wks[m * 64 + c] * vk;
        }
    }
    ((float4*)Q4)[gid] = make_float4(aq[0], aq[1], aq[2], aq[3]);
    ((float4*)K4)[gid] = make_float4(ak[0], ak[1], ak[2], ak[3]);
}

// K2a: per-(b, q-chunk) column max & sumexp over 512 queries. grid = B*8*16
__global__ void k2a_colstats(const float* __restrict__ Q4, const float* __restrict__ K4,
                             float* __restrict__ cpmax, float* __restrict__ cpsum) {
    __shared__ float4 Qs[512];
    int blk = blockIdx.x;
    int kblk = blk & 15;  blk >>= 4;
    int qch  = blk & 7;   blk >>= 3;
    int b    = blk;
    int tid = threadIdx.x;
    for (int i = tid; i < 512; i += 256)
        Qs[i] = ((const float4*)Q4)[b * NN + qch * 512 + i];
    __syncthreads();
    int k = kblk * 256 + tid;
    float4 kv = ((const float4*)K4)[b * NN + k];
    float mx = -1e30f;
    for (int i = 0; i < 512; ++i) {
        float4 q = Qs[i];
        float s = q.x * kv.x + q.y * kv.y + q.z * kv.z + q.w * kv.w;
        mx = fmaxf(mx, s);
    }
    float sum = 0.0f;
    for (int i = 0; i < 512; ++i) {
        float4 q = Qs[i];
        float s = q.x * kv.x + q.y * kv.y + q.z * kv.z + q.w * kv.w;
        sum += expf(s - mx);
    }
    cpmax[(b * NQCH + qch) * NN + k] = mx;
    cpsum[(b * NQCH + qch) * NN + k] = sum;
}

// K2b: merge chunk stats -> c[b][k] = m_k_r - 1 - log(colsum) - colmax
__global__ void k2b_cmerge(const float* __restrict__ cpmax, const float* __restrict__ cpsum,
                           const float* __restrict__ m_k, float* __restrict__ cvals) {
    int gid = blockIdx.x * 256 + threadIdx.x;  // B*N
    int b = gid >> 12, k = gid & 4095;
    float M = -1e30f;
    #pragma unroll
    for (int j = 0; j < NQCH; ++j) M = fmaxf(M, cpmax[(b * NQCH + j) * NN + k]);
    float S = 0.0f;
    #pragma unroll
    for (int j = 0; j < NQCH; ++j)
        S += cpsum[(b * NQCH + j) * NN + k] * expf(cpmax[(b * NQCH + j) * NN + k] - M);
    float mk = bilin32(m_k, b, k >> 6, k & 63);
    cvals[gid] = mk - 1.0f - logf(S) - M;
}

// K3: single-kernel top-8 over all 4096 keys + finalize cm/rmap.
// grid = B*16 blocks, 256 threads (one query per thread).
__global__ void k3_top8(const float* __restrict__ Q4, const float* __restrict__ K4,
                        const float* __restrict__ cvals, const float* __restrict__ mapin,
                        float* __restrict__ rmap, float* __restrict__ cmapf,
                        float* __restrict__ outp) {
    __shared__ float4 Ks[256];
    __shared__ float cs[256];
    int blk = blockIdx.x;
    int qblk = blk & 15;
    int b = blk >> 4;
    int tid = threadIdx.x;
    int q = qblk * 256 + tid;
    float4 qv = ((const float4*)Q4)[b * NN + q];
    float t[8];
    #pragma unroll
    for (int j = 0; j < 8; ++j) t[j] = -1e30f;   // ascending; t[0] = current min
    for (int ch = 0; ch < 16; ++ch) {
        __syncthreads();
        Ks[tid] = ((const float4*)K4)[b * NN + ch * 256 + tid];
        cs[tid] = cvals[b * NN + ch * 256 + tid];
        __syncthreads();
        for (int i = 0; i < 256; ++i) {
            float4 kv = Ks[i];
            float s = qv.x * kv.x + qv.y * kv.y + qv.z * kv.z + qv.w * kv.w + cs[i];
            if (s > t[0]) {
                t[0] = s;
                #pragma unroll
                for (int j = 0; j < 7; ++j)
                    if (t[j] > t[j + 1]) { float tmp = t[j]; t[j] = t[j + 1]; t[j + 1] = tmp; }
            }
        }
    }
    float sm = 0.0f;
    #pragma unroll
    for (int j = 0; j < 8; ++j) sm += expf(t[j]);
    float cmv = sm * 0.125f;
    int gid = b * NN + q;
    float mr = bilin32(mapin, b, q >> 6, q & 63);
    float cm = cmv * mr + mr;
    float rm = 1.0f / (1.0f + expf(cm));   // 1 - sigmoid(cm)
    rmap[gid] = rm;
    cmapf[gid] = cm;
    outp[OUT_CM_OFF + gid] = cm;
}

// K4: x1 = conv1x1(rmap*f, w_in) + b_in
__global__ void k4_conv1(const float* __restrict__ f, const float* __restrict__ rmap,
                         const float* __restrict__ w_in, const float* __restrict__ b_in,
                         float* __restrict__ xout) {
    __shared__ float ws_[1024];
    __shared__ float bs[32];
    int tid = threadIdx.x;
    for (int i = tid; i < 1024; i += 256) ws_[i] = w_in[i];
    if (tid < 32) bs[tid] = b_in[tid];
    __syncthreads();
    int gid = blockIdx.x * 256 + tid;      // b(2b) og(2b) hw(12b)
    int hw = gid & 4095;
    int og = (gid >> 12) & 3;
    int b  = gid >> 14;
    float rm = rmap[b * NN + hw];
    float acc[8];
    #pragma unroll
    for (int j = 0; j < 8; ++j) acc[j] = bs[og * 8 + j];
    const float* fb = f + (size_t)b * CH * NN + hw;
    for (int i = 0; i < 32; ++i) {
        float v = fb[i * NN] * rm;
        #pragma unroll
        for (int j = 0; j < 8; ++j) acc[j] += ws_[(og * 8 + j) * 32 + i] * v;
    }
    float* xo = xout + (size_t)b * CH * NN + (og * 8) * NN + hw;
    #pragma unroll
    for (int j = 0; j < 8; ++j) xo[j * NN] = acc[j];
}

// K5: 3x3 conv 32->32 (+bias, relu). grid = b*ty*tx*og = 256, block=256
__global__ void k5_conv3(const float* __restrict__ xin, const float* __restrict__ w,
                         const float* __restrict__ bias, float* __restrict__ xout, int relu) {
    __shared__ float tile[32][324];   // 18x18 per channel
    __shared__ float wsm[2304];       // 8 o x 32 i x 9
    __shared__ float bsm[8];
    int blk = blockIdx.x;
    int og = blk & 3;  blk >>= 2;
    int tx = blk & 3;  blk >>= 2;
    int ty = blk & 3;  blk >>= 2;
    int b  = blk;
    int tid = threadIdx.x;
    for (int i = tid; i < 2304; i += 256) wsm[i] = w[og * 2304 + i];
    if (tid < 8) bsm[tid] = bias[og * 8 + tid];
    int y0 = ty * 16 - 1, x0 = tx * 16 - 1;
    for (int i = tid; i < 32 * 324; i += 256) {
        int c = i / 324, r = i % 324;
        int yy = r / 18, xx = r % 18;
        int gy = y0 + yy, gx = x0 + xx;
        float v = 0.0f;
        if (gy >= 0 && gy < 64 && gx >= 0 && gx < 64)
            v = xin[((size_t)b * CH + c) * NN + gy * 64 + gx];
        tile[c][r] = v;
    }
    __syncthreads();
    int py = tid >> 4, px = tid & 15;
    float acc[8];
    #pragma unroll
    for (int j = 0; j < 8; ++j) acc[j] = bsm[j];
    for (int i = 0; i < 32; ++i) {
        const float* tr = &tile[i][py * 18 + px];
        float v00 = tr[0],  v01 = tr[1],  v02 = tr[2];
        float v10 = tr[18], v11 = tr[19], v12 = tr[20];
        float v20 = tr[36], v21 = tr[37], v22 = tr[38];
        #pragma unroll
        for (int j = 0; j < 8; ++j) {
            const float* wj = &wsm[j * 288 + i * 9];
            acc[j] += v00 * wj[0] + v01 * wj[1] + v02 * wj[2]
                    + v10 * wj[3] + v11 * wj[4] + v12 * wj[5]
                    + v20 * wj[6] + v21 * wj[7] + v22 * wj[8];
        }
    }
    float* xo = xout + (size_t)b * CH * NN + (ty * 16 + py) * 64 + tx * 16 + px;
    #pragma unroll
    for (int j = 0; j < 8; ++j) {
        float r_ = acc[j];
        if (relu) r_ = fmaxf(r_, 0.0f);
        xo[(og * 8 + j) * NN] = r_;
    }
}

// K6: final 3x3 conv 32->1 + b_out + corrected_map -> out (f32)
__global__ void k6_convout(const float* __restrict__ xin, const float* __restrict__ w_out,
                           const float* __restrict__ b_out, const float* __restrict__ cmapf,
                           float* __restrict__ outp) {
    __shared__ float wsm[288];
    int tid = threadIdx.x;
    for (int i = tid; i < 288; i += 256) wsm[i] = w_out[i];
    __syncthreads();
    int gid = blockIdx.x * 256 + tid;  // B*N
    int b = gid >> 12, hw = gid & 4095;
    int y = hw >> 6, x = hw & 63;
    float acc = b_out[0];
    for (int i = 0; i < 32; ++i) {
        const float* xi = xin + ((size_t)b * CH + i) * NN;
        #pragma unroll
        for (int ky = 0; ky < 3; ++ky) {
            int gy = y + ky - 1;
            if (gy < 0 || gy > 63) continue;
            #pragma unroll
            for (int kx = 0; kx < 3; ++kx) {
                int gx = x + kx - 1;
                if (gx < 0 || gx > 63) continue;
                acc += xi[gy * 64 + gx] * wsm[i * 9 + ky * 3 + kx];
            }
        }
    }
    acc += cmapf[gid];
    outp[OUT_O_OFF + gid] = acc;
}

// K7: copy x (f32 ws) -> d_out f32 (vectorized)
__global__ void k7_copyx(const float* __restrict__ x, float* __restrict__ outp) {
    int gid = blockIdx.x * 256 + threadIdx.x;   // 131072 float4s
    ((float4*)(outp + OUT_X_OFF))[gid] = ((const float4*)x)[gid];
}

extern "C" void kernel_launch(void* const* d_in, const int* in_sizes, int n_in,
                              void* d_out, int out_size, void* d_ws, size_t ws_size,
                              hipStream_t stream) {
    // Input-order detection (host-side, deterministic, graph-safe).
    int i_f, i_map, i_fq, i_fk, i_mk, i_wq, i_wk, i_win, i_bin, i_wmid, i_bmid, i_wout, i_bout;
    if (n_in >= 13 && in_sizes[0] == 32 && in_sizes[1] == 96) {
        // sorted-by-name
        i_bin = 0; i_bmid = 1; i_bout = 2; i_f = 3; i_fk = 4; i_fq = 5;
        i_mk = 6; i_map = 7; i_win = 8; i_wmid = 9; i_wout = 10; i_wk = 11; i_wq = 12;
    } else {
        // documented dict order (confirmed by rounds 2->3 identical behavior)
        i_f = 0; i_map = 1; i_fq = 2; i_fk = 3; i_mk = 4; i_wq = 5; i_wk = 6;
        i_win = 7; i_bin = 8; i_wmid = 9; i_bmid = 10; i_wout = 11; i_bout = 12;
    }

    const float* f     = (const float*)d_in[i_f];
    const float* mapin = (const float*)d_in[i_map];
    const float* f_q   = (const float*)d_in[i_fq];
    const float* f_k   = (const float*)d_in[i_fk];
    const float* m_k   = (const float*)d_in[i_mk];
    const float* wq    = (const float*)d_in[i_wq];
    const float* wk    = (const float*)d_in[i_wk];
    const float* w_in  = (const float*)d_in[i_win];
    const float* b_in  = (const float*)d_in[i_bin];
    const float* w_mid = (const float*)d_in[i_wmid];
    const float* b_mid = (const float*)d_in[i_bmid];
    const float* w_out = (const float*)d_in[i_wout];
    const float* b_out = (const float*)d_in[i_bout];
    float* outp = (float*)d_out;   // reference outputs are float32
    float* ws = (float*)d_ws;

    float* PP    = ws + PP_OFF;
    float* Q4    = ws + Q4_OFF;
    float* K4    = ws + K4_OFF;
    float* CV    = ws + CV_OFF;
    float* CPMAX = ws + CPMAX_OFF;
    float* CPSUM = ws + CPSUM_OFF;
    float* RMAP  = ws + RMAP_OFF;
    float* CMAPF = ws + CMAPF_OFF;
    float* XA    = ws + XA_OFF;
    float* XB    = ws + XB_OFF;

    k0_posproj<<<1, 64, 0, stream>>>(wq, wk, PP);
    k1_qk<<<64, 256, 0, stream>>>(f_q, f_k, wq, wk, PP, Q4, K4);
    k2a_colstats<<<BB * NQCH * 16, 256, 0, stream>>>(Q4, K4, CPMAX, CPSUM);
    k2b_cmerge<<<64, 256, 0, stream>>>(CPMAX, CPSUM, m_k, CV);
    k3_top8<<<BB * 16, 256, 0, stream>>>(Q4, K4, CV, mapin, RMAP, CMAPF, outp);
    k4_conv1<<<256, 256, 0, stream>>>(f, RMAP, w_in, b_in, XA);
    k5_conv3<<<256, 256, 0, stream>>>(XA, w_mid + 0 * 9216, b_mid + 0 * 32, XB, 1);
    k5_conv3<<<256, 256, 0, stream>>>(XB, w_mid + 1 * 9216, b_mid + 1 * 32, XA, 1);
    k5_conv3<<<256, 256, 0, stream>>>(XA, w_mid + 2 * 9216, b_mid + 2 * 32, XB, 1);
    k7_copyx<<<512, 256, 0, stream>>>(XB, outp);
    k6_convout<<<64, 256, 0, stream>>>(XB, w_out, b_out, CMAPF, outp);
}

// Round 5
// 322.638 us; speedup vs baseline: 1.9293x; 1.9293x over previous
//
#include <hip/hip_runtime.h>
#include <hip/hip_bf16.h>
#include <math.h>

// Problem constants
#define BB 4
#define CIN 64
#define CH 32
#define HH 64
#define WW 64
#define NN 4096           // H*W
#define MCH 4
#define NQCH 32           // q-chunks for column stats (chunk = 128 queries)

// ws layout (floats). Total 1,229,824 floats = 4.69 MiB.
// Temporal aliasing (safe; stream-ordered):
//   CPMAX/CPSUM live only k2a->k2b.
//   RMAP/CMAPF/XA/XB alias that region, written k3/k4/k5 (all after k2b).
#define PP_OFF     0          // 1024
#define Q4_OFF     1024       // 65536
#define K4_OFF     66560      // 65536
#define CV_OFF     132096     // 16384
#define CPMAX_OFF  148480     // 524288 (B*32*N; dead after k2b)
#define CPSUM_OFF  672768     // 524288 (dead after k2b)
#define RMAP_OFF   148480     // 16384  (aliases CPMAX head, written in k3)
#define CMAPF_OFF  164864     // 16384  (aliases CPMAX,   written in k3)
#define XA_OFF     181248     // 524288 (aliases CPMAX tail+CPSUM head, written in k4)
#define XB_OFF     705536     // 524288 (aliases CPSUM tail, written in k5)
// end = 1229824 floats = 4,919,296 bytes

// out layout (FLOAT32 elements): x | out | corrected_map
#define OUT_X_OFF   0
#define OUT_O_OFF   524288
#define OUT_CM_OFF  540672

__device__ __forceinline__ float bilin32(const float* src, int b, int y, int x) {
    float sy = 0.5f * y - 0.25f;
    float sx = 0.5f * x - 0.25f;
    float fy0 = floorf(sy), fx0 = floorf(sx);
    int y0 = (int)fy0, x0 = (int)fx0;
    float fy = sy - fy0, fx = sx - fx0;
    int y0c = min(max(y0, 0), 31), y1c = min(max(y0 + 1, 0), 31);
    int x0c = min(max(x0, 0), 31), x1c = min(max(x0 + 1, 0), 31);
    const float* p = src + b * 1024;
    float v00 = p[y0c * 32 + x0c], v01 = p[y0c * 32 + x1c];
    float v10 = p[y1c * 32 + x0c], v11 = p[y1c * 32 + x1c];
    float v0 = v00 + fx * (v01 - v00);
    float v1 = v10 + fx * (v11 - v10);
    return v0 + fy * (v1 - v0);
}

// K0: pos embedding projected through wq/wk, decomposed per coordinate (exact).
__global__ void k0_posproj(const float* __restrict__ wq, const float* __restrict__ wk,
                           float* __restrict__ pp) {
    int t = threadIdx.x;  // coordinate 0..63
    float coord = (float)(t + 1);
    float qy[4] = {0,0,0,0}, qx[4] = {0,0,0,0}, ky[4] = {0,0,0,0}, kx[4] = {0,0,0,0};
    for (int c = 0; c < 32; ++c) {
        float e = (2.0f * (float)(c / 2)) / 32.0f;
        float dim = powf(10000.0f, e);
        float ang = coord / dim;
        float pr = (c & 1) ? cosf(ang) : sinf(ang);
        #pragma unroll
        for (int m = 0; m < 4; ++m) {
            qy[m] += wq[m * 64 + c] * pr;
            qx[m] += wq[m * 64 + 32 + c] * pr;
            ky[m] += wk[m * 64 + c] * pr;
            kx[m] += wk[m * 64 + 32 + c] * pr;
        }
    }
    #pragma unroll
    for (int m = 0; m < 4; ++m) {
        pp[0 * 256 + m * 64 + t] = qy[m];
        pp[1 * 256 + m * 64 + t] = qx[m];
        pp[2 * 256 + m * 64 + t] = ky[m];
        pp[3 * 256 + m * 64 + t] = kx[m];
    }
}

// K1: Q[b,hw,m], K[b,hw,m] projections
__global__ void k1_qk(const float* __restrict__ fq, const float* __restrict__ fk,
                      const float* __restrict__ wq, const float* __restrict__ wk,
                      const float* __restrict__ pp,
                      float* __restrict__ Q4, float* __restrict__ K4) {
    __shared__ float wqs[256], wks[256];
    int tid = threadIdx.x;
    wqs[tid] = wq[tid];
    wks[tid] = wk[tid];
    __syncthreads();
    int gid = blockIdx.x * 256 + tid;           // 0..B*N
    int b = gid >> 12, hw = gid & 4095;
    int y = hw >> 6, x = hw & 63;
    float aq[4], ak[4];
    #pragma unroll
    for (int m = 0; m < 4; ++m) {
        aq[m] = pp[0 * 256 + m * 64 + y] + pp[1 * 256 + m * 64 + x];
        ak[m] = pp[2 * 256 + m * 64 + y] + pp[3 * 256 + m * 64 + x];
    }
    const float* fqb = fq + b * (CIN * NN) + hw;
    const float* fkb = fk + b * (CIN * NN) + hw;
    for (int c = 0; c < 64; ++c) {
        float vq = fqb[c * NN];
        float vk = fkb[c * NN];
        #pragma unroll
        for (int m = 0; m < 4; ++m) {
            aq[m] += wqs[m * 64 + c] * vq;
            ak[m] += wks[m * 64 + c] * vk;
        }
    }
    ((float4*)Q4)[gid] = make_float4(aq[0], aq[1], aq[2], aq[3]);
    ((float4*)K4)[gid] = make_float4(ak[0], ak[1], ak[2], ak[3]);
}

// K2a: per-(b, q-chunk of 128) column max & sumexp. grid = B*32*16 = 2048
__global__ void k2a_colstats(const float* __restrict__ Q4, const float* __restrict__ K4,
                             float* __restrict__ cpmax, float* __restrict__ cpsum) {
    __shared__ float4 Qs[128];
    int blk = blockIdx.x;
    int kblk = blk & 15;  blk >>= 4;
    int qch  = blk & 31;  blk >>= 5;
    int b    = blk;
    int tid = threadIdx.x;
    if (tid < 128)
        Qs[tid] = ((const float4*)Q4)[b * NN + qch * 128 + tid];
    __syncthreads();
    int k = kblk * 256 + tid;
    float4 kv = ((const float4*)K4)[b * NN + k];
    float mx = -1e30f;
    #pragma unroll 4
    for (int i = 0; i < 128; ++i) {
        float4 q = Qs[i];
        float s = q.x * kv.x + q.y * kv.y + q.z * kv.z + q.w * kv.w;
        mx = fmaxf(mx, s);
    }
    float sum = 0.0f;
    #pragma unroll 4
    for (int i = 0; i < 128; ++i) {
        float4 q = Qs[i];
        float s = q.x * kv.x + q.y * kv.y + q.z * kv.z + q.w * kv.w;
        sum += expf(s - mx);
    }
    cpmax[(b * NQCH + qch) * NN + k] = mx;
    cpsum[(b * NQCH + qch) * NN + k] = sum;
}

// K2b: merge chunk stats -> c[b][k] = m_k_r - 1 - log(colsum) - colmax
__global__ void k2b_cmerge(const float* __restrict__ cpmax, const float* __restrict__ cpsum,
                           const float* __restrict__ m_k, float* __restrict__ cvals) {
    int gid = blockIdx.x * 256 + threadIdx.x;  // B*N
    int b = gid >> 12, k = gid & 4095;
    float M = -1e30f;
    #pragma unroll
    for (int j = 0; j < NQCH; ++j) M = fmaxf(M, cpmax[(b * NQCH + j) * NN + k]);
    float S = 0.0f;
    #pragma unroll
    for (int j = 0; j < NQCH; ++j)
        S += cpsum[(b * NQCH + j) * NN + k] * expf(cpmax[(b * NQCH + j) * NN + k] - M);
    float mk = bilin32(m_k, b, k >> 6, k & 63);
    cvals[gid] = mk - 1.0f - logf(S) - M;
}

// K3: wave-per-query top-8. grid = B*1024 blocks (4 queries/block, 1 wave each).
// Lane scans 64 keys (coalesced), register top-8, then 8-round shfl argmax-pop merge.
__global__ void k3_top8(const float* __restrict__ Q4, const float* __restrict__ K4,
                        const float* __restrict__ cvals, const float* __restrict__ mapin,
                        float* __restrict__ rmap, float* __restrict__ cmapf,
                        float* __restrict__ outp) {
    int blk = blockIdx.x;
    int b = blk >> 10;
    int qbase = (blk & 1023) * 4;
    int tid = threadIdx.x;
    int wave = tid >> 6;
    int lane = tid & 63;
    int q = qbase + wave;
    float4 qv = ((const float4*)Q4)[b * NN + q];
    float t0 = -1e30f, t1 = -1e30f, t2 = -1e30f, t3 = -1e30f;
    float t4 = -1e30f, t5 = -1e30f, t6 = -1e30f, t7 = -1e30f;  // ascending; t7 = max
    const float4* Kb = (const float4*)K4 + b * NN;
    const float* cb = cvals + b * NN;
    #pragma unroll 4
    for (int i = 0; i < 64; ++i) {
        int k = i * 64 + lane;
        float4 kv = Kb[k];
        float s = qv.x * kv.x + qv.y * kv.y + qv.z * kv.z + qv.w * kv.w + cb[k];
        if (s > t0) {
            t0 = s;
            if (t0 > t1) { float z = t0; t0 = t1; t1 = z; }
            if (t1 > t2) { float z = t1; t1 = t2; t2 = z; }
            if (t2 > t3) { float z = t2; t2 = t3; t3 = z; }
            if (t3 > t4) { float z = t3; t3 = t4; t4 = z; }
            if (t4 > t5) { float z = t4; t4 = t5; t5 = z; }
            if (t5 > t6) { float z = t5; t5 = t6; t6 = z; }
            if (t6 > t7) { float z = t6; t6 = t7; t7 = z; }
        }
    }
    // 8-round wave argmax-pop merge over 64 lanes x 8 candidates
    float sm = 0.0f;
    #pragma unroll
    for (int r = 0; r < 8; ++r) {
        float v = t7;
        int ln = lane;
        #pragma unroll
        for (int off = 32; off >= 1; off >>= 1) {
            float ov = __shfl_xor(v, off);
            int ol = __shfl_xor(ln, off);
            if (ov > v || (ov == v && ol < ln)) { v = ov; ln = ol; }
        }
        sm += expf(v);
        if (lane == ln) {  // pop my max: shift up, keep sorted ascending
            t7 = t6; t6 = t5; t5 = t4; t4 = t3; t3 = t2; t2 = t1; t1 = t0; t0 = -1e30f;
        }
    }
    if (lane == 0) {
        float cmv = sm * 0.125f;
        int gid = b * NN + q;
        float mr = bilin32(mapin, b, q >> 6, q & 63);
        float cm = cmv * mr + mr;
        float rm = 1.0f / (1.0f + expf(cm));   // 1 - sigmoid(cm)
        rmap[gid] = rm;
        cmapf[gid] = cm;
        outp[OUT_CM_OFF + gid] = cm;
    }
}

// K4: x1 = conv1x1(rmap*f, w_in) + b_in
__global__ void k4_conv1(const float* __restrict__ f, const float* __restrict__ rmap,
                         const float* __restrict__ w_in, const float* __restrict__ b_in,
                         float* __restrict__ xout) {
    __shared__ float ws_[1024];
    __shared__ float bs[32];
    int tid = threadIdx.x;
    for (int i = tid; i < 1024; i += 256) ws_[i] = w_in[i];
    if (tid < 32) bs[tid] = b_in[tid];
    __syncthreads();
    int gid = blockIdx.x * 256 + tid;      // b(2b) og(2b) hw(12b)
    int hw = gid & 4095;
    int og = (gid >> 12) & 3;
    int b  = gid >> 14;
    float rm = rmap[b * NN + hw];
    float acc[8];
    #pragma unroll
    for (int j = 0; j < 8; ++j) acc[j] = bs[og * 8 + j];
    const float* fb = f + (size_t)b * CH * NN + hw;
    for (int i = 0; i < 32; ++i) {
        float v = fb[i * NN] * rm;
        #pragma unroll
        for (int j = 0; j < 8; ++j) acc[j] += ws_[(og * 8 + j) * 32 + i] * v;
    }
    float* xo = xout + (size_t)b * CH * NN + (og * 8) * NN + hw;
    #pragma unroll
    for (int j = 0; j < 8; ++j) xo[j * NN] = acc[j];
}

// K5: 3x3 conv 32->32 (+bias, relu). grid = b*ty*tx*og = 256, block=256
__global__ void k5_conv3(const float* __restrict__ xin, const float* __restrict__ w,
                         const float* __restrict__ bias, float* __restrict__ xout, int relu) {
    __shared__ float tile[32][324];   // 18x18 per channel
    __shared__ float wsm[2304];       // 8 o x 32 i x 9
    __shared__ float bsm[8];
    int blk = blockIdx.x;
    int og = blk & 3;  blk >>= 2;
    int tx = blk & 3;  blk >>= 2;
    int ty = blk & 3;  blk >>= 2;
    int b  = blk;
    int tid = threadIdx.x;
    for (int i = tid; i < 2304; i += 256) wsm[i] = w[og * 2304 + i];
    if (tid < 8) bsm[tid] = bias[og * 8 + tid];
    int y0 = ty * 16 - 1, x0 = tx * 16 - 1;
    for (int i = tid; i < 32 * 324; i += 256) {
        int c = i / 324, r = i % 324;
        int yy = r / 18, xx = r % 18;
        int gy = y0 + yy, gx = x0 + xx;
        float v = 0.0f;
        if (gy >= 0 && gy < 64 && gx >= 0 && gx < 64)
            v = xin[((size_t)b * CH + c) * NN + gy * 64 + gx];
        tile[c][r] = v;
    }
    __syncthreads();
    int py = tid >> 4, px = tid & 15;
    float acc[8];
    #pragma unroll
    for (int j = 0; j < 8; ++j) acc[j] = bsm[j];
    for (int i = 0; i < 32; ++i) {
        const float* tr = &tile[i][py * 18 + px];
        float v00 = tr[0],  v01 = tr[1],  v02 = tr[2];
        float v10 = tr[18], v11 = tr[19], v12 = tr[20];
        float v20 = tr[36], v21 = tr[37], v22 = tr[38];
        #pragma unroll
        for (int j = 0; j < 8; ++j) {
            const float* wj = &wsm[j * 288 + i * 9];
            acc[j] += v00 * wj[0] + v01 * wj[1] + v02 * wj[2]
                    + v10 * wj[3] + v11 * wj[4] + v12 * wj[5]
                    + v20 * wj[6] + v21 * wj[7] + v22 * wj[8];
        }
    }
    float* xo = xout + (size_t)b * CH * NN + (ty * 16 + py) * 64 + tx * 16 + px;
    #pragma unroll
    for (int j = 0; j < 8; ++j) {
        float r_ = acc[j];
        if (relu) r_ = fmaxf(r_, 0.0f);
        xo[(og * 8 + j) * NN] = r_;
    }
}

// K6: final 3x3 conv 32->1 + b_out + corrected_map -> out (f32)
__global__ void k6_convout(const float* __restrict__ xin, const float* __restrict__ w_out,
                           const float* __restrict__ b_out, const float* __restrict__ cmapf,
                           float* __restrict__ outp) {
    __shared__ float wsm[288];
    int tid = threadIdx.x;
    for (int i = tid; i < 288; i += 256) wsm[i] = w_out[i];
    __syncthreads();
    int gid = blockIdx.x * 256 + tid;  // B*N
    int b = gid >> 12, hw = gid & 4095;
    int y = hw >> 6, x = hw & 63;
    float acc = b_out[0];
    for (int i = 0; i < 32; ++i) {
        const float* xi = xin + ((size_t)b * CH + i) * NN;
        #pragma unroll
        for (int ky = 0; ky < 3; ++ky) {
            int gy = y + ky - 1;
            if (gy < 0 || gy > 63) continue;
            #pragma unroll
            for (int kx = 0; kx < 3; ++kx) {
                int gx = x + kx - 1;
                if (gx < 0 || gx > 63) continue;
                acc += xi[gy * 64 + gx] * wsm[i * 9 + ky * 3 + kx];
            }
        }
    }
    acc += cmapf[gid];
    outp[OUT_O_OFF + gid] = acc;
}

// K7: copy x (f32 ws) -> d_out f32 (vectorized)
__global__ void k7_copyx(const float* __restrict__ x, float* __restrict__ outp) {
    int gid = blockIdx.x * 256 + threadIdx.x;   // 131072 float4s
    ((float4*)(outp + OUT_X_OFF))[gid] = ((const float4*)x)[gid];
}

extern "C" void kernel_launch(void* const* d_in, const int* in_sizes, int n_in,
                              void* d_out, int out_size, void* d_ws, size_t ws_size,
                              hipStream_t stream) {
    // documented dict order (confirmed)
    const float* f     = (const float*)d_in[0];
    const float* mapin = (const float*)d_in[1];
    const float* f_q   = (const float*)d_in[2];
    const float* f_k   = (const float*)d_in[3];
    const float* m_k   = (const float*)d_in[4];
    const float* wq    = (const float*)d_in[5];
    const float* wk    = (const float*)d_in[6];
    const float* w_in  = (const float*)d_in[7];
    const float* b_in  = (const float*)d_in[8];
    const float* w_mid = (const float*)d_in[9];
    const float* b_mid = (const float*)d_in[10];
    const float* w_out = (const float*)d_in[11];
    const float* b_out = (const float*)d_in[12];
    float* outp = (float*)d_out;   // reference outputs are float32
    float* ws = (float*)d_ws;

    float* PP    = ws + PP_OFF;
    float* Q4    = ws + Q4_OFF;
    float* K4    = ws + K4_OFF;
    float* CV    = ws + CV_OFF;
    float* CPMAX = ws + CPMAX_OFF;
    float* CPSUM = ws + CPSUM_OFF;
    float* RMAP  = ws + RMAP_OFF;
    float* CMAPF = ws + CMAPF_OFF;
    float* XA    = ws + XA_OFF;
    float* XB    = ws + XB_OFF;

    k0_posproj<<<1, 64, 0, stream>>>(wq, wk, PP);
    k1_qk<<<64, 256, 0, stream>>>(f_q, f_k, wq, wk, PP, Q4, K4);
    k2a_colstats<<<BB * NQCH * 16, 256, 0, stream>>>(Q4, K4, CPMAX, CPSUM);
    k2b_cmerge<<<64, 256, 0, stream>>>(CPMAX, CPSUM, m_k, CV);
    k3_top8<<<BB * 1024, 256, 0, stream>>>(Q4, K4, CV, mapin, RMAP, CMAPF, outp);
    k4_conv1<<<256, 256, 0, stream>>>(f, RMAP, w_in, b_in, XA);
    k5_conv3<<<256, 256, 0, stream>>>(XA, w_mid + 0 * 9216, b_mid + 0 * 32, XB, 1);
    k5_conv3<<<256, 256, 0, stream>>>(XB, w_mid + 1 * 9216, b_mid + 1 * 32, XA, 1);
    k5_conv3<<<256, 256, 0, stream>>>(XA, w_mid + 2 * 9216, b_mid + 2 * 32, XB, 1);
    k7_copyx<<<512, 256, 0, stream>>>(XB, outp);
    k6_convout<<<64, 256, 0, stream>>>(XB, w_out, b_out, CMAPF, outp);
}

// Round 6
// 269.985 us; speedup vs baseline: 2.3055x; 1.1950x over previous
//
#include <hip/hip_runtime.h>
#include <hip/hip_bf16.h>
#include <math.h>

// Problem constants
#define BB 4
#define CIN 64
#define CH 32
#define HH 64
#define WW 64
#define NN 4096           // H*W
#define MCH 4
#define NQCH 32           // q-chunks for column stats (chunk = 128 queries)

// ws layout (floats). Total 1,229,824 floats = 4.69 MiB (proven size).
// Temporal aliasing: CPMAX/CPSUM live only k2a->k2b; RMAP/CMAPF/XA alias
// that region (written k3/k4, after k2b).
#define PP_OFF     0          // 1024
#define Q4_OFF     1024       // 65536
#define K4_OFF     66560      // 65536
#define CV_OFF     132096     // 16384
#define CPMAX_OFF  148480     // 524288 (dead after k2b)
#define CPSUM_OFF  672768     // 524288 (dead after k2b)
#define RMAP_OFF   148480     // 16384  (aliases CPMAX head)
#define CMAPF_OFF  164864     // 16384
#define XA_OFF     181248     // 524288
#define XB_OFF     705536     // 524288
// end = 1229824 floats

// out layout (FLOAT32 elements): x | out | corrected_map
#define OUT_X_OFF   0
#define OUT_O_OFF   524288
#define OUT_CM_OFF  540672

__device__ __forceinline__ float bilin32(const float* src, int b, int y, int x) {
    float sy = 0.5f * y - 0.25f;
    float sx = 0.5f * x - 0.25f;
    float fy0 = floorf(sy), fx0 = floorf(sx);
    int y0 = (int)fy0, x0 = (int)fx0;
    float fy = sy - fy0, fx = sx - fx0;
    int y0c = min(max(y0, 0), 31), y1c = min(max(y0 + 1, 0), 31);
    int x0c = min(max(x0, 0), 31), x1c = min(max(x0 + 1, 0), 31);
    const float* p = src + b * 1024;
    float v00 = p[y0c * 32 + x0c], v01 = p[y0c * 32 + x1c];
    float v10 = p[y1c * 32 + x0c], v11 = p[y1c * 32 + x1c];
    float v0 = v00 + fx * (v01 - v00);
    float v1 = v10 + fx * (v11 - v10);
    return v0 + fy * (v1 - v0);
}

// K0: pos embedding projected through wq/wk, per coordinate (exact).
__global__ void k0_posproj(const float* __restrict__ wq, const float* __restrict__ wk,
                           float* __restrict__ pp) {
    int t = threadIdx.x;  // coordinate 0..63
    float coord = (float)(t + 1);
    float qy[4] = {0,0,0,0}, qx[4] = {0,0,0,0}, ky[4] = {0,0,0,0}, kx[4] = {0,0,0,0};
    for (int c = 0; c < 32; ++c) {
        float e = (2.0f * (float)(c / 2)) / 32.0f;
        float dim = powf(10000.0f, e);
        float ang = coord / dim;
        float pr = (c & 1) ? cosf(ang) : sinf(ang);
        #pragma unroll
        for (int m = 0; m < 4; ++m) {
            qy[m] += wq[m * 64 + c] * pr;
            qx[m] += wq[m * 64 + 32 + c] * pr;
            ky[m] += wk[m * 64 + c] * pr;
            kx[m] += wk[m * 64 + 32 + c] * pr;
        }
    }
    #pragma unroll
    for (int m = 0; m < 4; ++m) {
        pp[0 * 256 + m * 64 + t] = qy[m];
        pp[1 * 256 + m * 64 + t] = qx[m];
        pp[2 * 256 + m * 64 + t] = ky[m];
        pp[3 * 256 + m * 64 + t] = kx[m];
    }
}

// K1: Q/K projections, channel-split 4x16 + LDS reduce. grid = B*N/64 = 256
__global__ void k1_qk(const float* __restrict__ fq, const float* __restrict__ fk,
                      const float* __restrict__ wq, const float* __restrict__ wk,
                      const float* __restrict__ pp,
                      float* __restrict__ Q4, float* __restrict__ K4) {
    __shared__ float wqs[256], wks[256];
    __shared__ float red[256][9];   // [thread][8 partials], padded to 9 (bank)
    int tid = threadIdx.x;
    wqs[tid] = wq[tid];
    wks[tid] = wk[tid];
    __syncthreads();
    int qi = tid & 63, g = tid >> 6;
    int gid = blockIdx.x * 64 + qi;
    int b = gid >> 12, hw = gid & 4095;
    const float* fqb = fq + (size_t)b * CIN * NN + hw;
    const float* fkb = fk + (size_t)b * CIN * NN + hw;
    float aq[4] = {0,0,0,0}, ak[4] = {0,0,0,0};
    int c0 = g * 16;
    #pragma unroll 4
    for (int c = c0; c < c0 + 16; ++c) {
        float vq = fqb[c * NN];
        float vk = fkb[c * NN];
        #pragma unroll
        for (int m = 0; m < 4; ++m) {
            aq[m] += wqs[m * 64 + c] * vq;
            ak[m] += wks[m * 64 + c] * vk;
        }
    }
    #pragma unroll
    for (int m = 0; m < 4; ++m) { red[tid][m] = aq[m]; red[tid][4 + m] = ak[m]; }
    __syncthreads();
    if (tid < 64) {
        int y = hw >> 6, x = hw & 63;
        float q4[4], k4[4];
        #pragma unroll
        for (int m = 0; m < 4; ++m) {
            q4[m] = red[tid][m] + red[tid + 64][m] + red[tid + 128][m] + red[tid + 192][m]
                  + pp[0 * 256 + m * 64 + y] + pp[1 * 256 + m * 64 + x];
            k4[m] = red[tid][4 + m] + red[tid + 64][4 + m] + red[tid + 128][4 + m] + red[tid + 192][4 + m]
                  + pp[2 * 256 + m * 64 + y] + pp[3 * 256 + m * 64 + x];
        }
        ((float4*)Q4)[gid] = make_float4(q4[0], q4[1], q4[2], q4[3]);
        ((float4*)K4)[gid] = make_float4(k4[0], k4[1], k4[2], k4[3]);
    }
}

// K2a: per-(b, q-chunk of 128) column max & sumexp. grid = B*32*16 = 2048
__global__ void k2a_colstats(const float* __restrict__ Q4, const float* __restrict__ K4,
                             float* __restrict__ cpmax, float* __restrict__ cpsum) {
    __shared__ float4 Qs[128];
    int blk = blockIdx.x;
    int kblk = blk & 15;  blk >>= 4;
    int qch  = blk & 31;  blk >>= 5;
    int b    = blk;
    int tid = threadIdx.x;
    if (tid < 128)
        Qs[tid] = ((const float4*)Q4)[b * NN + qch * 128 + tid];
    __syncthreads();
    int k = kblk * 256 + tid;
    float4 kv = ((const float4*)K4)[b * NN + k];
    float mx = -1e30f;
    #pragma unroll 4
    for (int i = 0; i < 128; ++i) {
        float4 q = Qs[i];
        float s = q.x * kv.x + q.y * kv.y + q.z * kv.z + q.w * kv.w;
        mx = fmaxf(mx, s);
    }
    float sum = 0.0f;
    #pragma unroll 4
    for (int i = 0; i < 128; ++i) {
        float4 q = Qs[i];
        float s = q.x * kv.x + q.y * kv.y + q.z * kv.z + q.w * kv.w;
        sum += expf(s - mx);
    }
    cpmax[(b * NQCH + qch) * NN + k] = mx;
    cpsum[(b * NQCH + qch) * NN + k] = sum;
}

// K2b: merge chunk stats -> c[b][k] = m_k_r - 1 - log(colsum) - colmax
__global__ void k2b_cmerge(const float* __restrict__ cpmax, const float* __restrict__ cpsum,
                           const float* __restrict__ m_k, float* __restrict__ cvals) {
    int gid = blockIdx.x * 256 + threadIdx.x;  // B*N
    int b = gid >> 12, k = gid & 4095;
    float M = -1e30f;
    #pragma unroll
    for (int j = 0; j < NQCH; ++j) M = fmaxf(M, cpmax[(b * NQCH + j) * NN + k]);
    float S = 0.0f;
    #pragma unroll
    for (int j = 0; j < NQCH; ++j)
        S += cpsum[(b * NQCH + j) * NN + k] * expf(cpmax[(b * NQCH + j) * NN + k] - M);
    float mk = bilin32(m_k, b, k >> 6, k & 63);
    cvals[gid] = mk - 1.0f - logf(S) - M;
}

// K3: wave-per-query top-8. grid = B*1024 blocks (4 queries/block, 1 wave each).
__global__ void k3_top8(const float* __restrict__ Q4, const float* __restrict__ K4,
                        const float* __restrict__ cvals, const float* __restrict__ mapin,
                        float* __restrict__ rmap, float* __restrict__ cmapf,
                        float* __restrict__ outp) {
    int blk = blockIdx.x;
    int b = blk >> 10;
    int qbase = (blk & 1023) * 4;
    int tid = threadIdx.x;
    int wave = tid >> 6;
    int lane = tid & 63;
    int q = qbase + wave;
    float4 qv = ((const float4*)Q4)[b * NN + q];
    float t0 = -1e30f, t1 = -1e30f, t2 = -1e30f, t3 = -1e30f;
    float t4 = -1e30f, t5 = -1e30f, t6 = -1e30f, t7 = -1e30f;  // ascending
    const float4* Kb = (const float4*)K4 + b * NN;
    const float* cb = cvals + b * NN;
    #pragma unroll 4
    for (int i = 0; i < 64; ++i) {
        int k = i * 64 + lane;
        float4 kv = Kb[k];
        float s = qv.x * kv.x + qv.y * kv.y + qv.z * kv.z + qv.w * kv.w + cb[k];
        if (s > t0) {
            t0 = s;
            if (t0 > t1) { float z = t0; t0 = t1; t1 = z; }
            if (t1 > t2) { float z = t1; t1 = t2; t2 = z; }
            if (t2 > t3) { float z = t2; t2 = t3; t3 = z; }
            if (t3 > t4) { float z = t3; t3 = t4; t4 = z; }
            if (t4 > t5) { float z = t4; t4 = t5; t5 = z; }
            if (t5 > t6) { float z = t5; t5 = t6; t6 = z; }
            if (t6 > t7) { float z = t6; t6 = t7; t7 = z; }
        }
    }
    float sm = 0.0f;
    #pragma unroll
    for (int r = 0; r < 8; ++r) {
        float v = t7;
        int ln = lane;
        #pragma unroll
        for (int off = 32; off >= 1; off >>= 1) {
            float ov = __shfl_xor(v, off);
            int ol = __shfl_xor(ln, off);
            if (ov > v || (ov == v && ol < ln)) { v = ov; ln = ol; }
        }
        sm += expf(v);
        if (lane == ln) {
            t7 = t6; t6 = t5; t5 = t4; t4 = t3; t3 = t2; t2 = t1; t1 = t0; t0 = -1e30f;
        }
    }
    if (lane == 0) {
        float cmv = sm * 0.125f;
        int gid = b * NN + q;
        float mr = bilin32(mapin, b, q >> 6, q & 63);
        float cm = cmv * mr + mr;
        float rm = 1.0f / (1.0f + expf(cm));
        rmap[gid] = rm;
        cmapf[gid] = cm;
        outp[OUT_CM_OFF + gid] = cm;
    }
}

// K4: x1 = conv1x1(rmap*f, w_in) + b_in. og-split 8 -> grid 512
__global__ void k4_conv1(const float* __restrict__ f, const float* __restrict__ rmap,
                         const float* __restrict__ w_in, const float* __restrict__ b_in,
                         float* __restrict__ xout) {
    __shared__ float ws_[1024];
    __shared__ float bs[32];
    int tid = threadIdx.x;
    for (int i = tid; i < 1024; i += 256) ws_[i] = w_in[i];
    if (tid < 32) bs[tid] = b_in[tid];
    __syncthreads();
    int gid = blockIdx.x * 256 + tid;      // b(2b) og(3b) hw(12b)
    int hw = gid & 4095;
    int og = (gid >> 12) & 7;
    int b  = gid >> 15;
    float rm = rmap[b * NN + hw];
    float acc[4];
    #pragma unroll
    for (int j = 0; j < 4; ++j) acc[j] = bs[og * 4 + j];
    const float* fb = f + (size_t)b * CH * NN + hw;
    for (int i = 0; i < 32; ++i) {
        float v = fb[i * NN] * rm;
        #pragma unroll
        for (int j = 0; j < 4; ++j) acc[j] += ws_[(og * 4 + j) * 32 + i] * v;
    }
    float* xo = xout + (size_t)b * CH * NN + (og * 4) * NN + hw;
    #pragma unroll
    for (int j = 0; j < 4; ++j) xo[j * NN] = acc[j];
}

// K5: 3x3 conv 32->32 (+bias, relu). og-split 8 -> grid = b*ty*tx*og = 512
// outx != null: also store result to outx (f32 x output, layer 3)
__global__ void k5_conv3(const float* __restrict__ xin, const float* __restrict__ w,
                         const float* __restrict__ bias, float* __restrict__ xout,
                         float* __restrict__ outx) {
    __shared__ float tile[32][324];   // 18x18 per channel
    __shared__ float wsm[1152];       // 4 o x 32 i x 9
    __shared__ float bsm[4];
    int blk = blockIdx.x;
    int og = blk & 7;  blk >>= 3;
    int tx = blk & 3;  blk >>= 2;
    int ty = blk & 3;  blk >>= 2;
    int b  = blk;
    int tid = threadIdx.x;
    for (int i = tid; i < 1152; i += 256) wsm[i] = w[og * 1152 + i];
    if (tid < 4) bsm[tid] = bias[og * 4 + tid];
    int y0 = ty * 16 - 1, x0 = tx * 16 - 1;
    for (int i = tid; i < 32 * 324; i += 256) {
        int c = i / 324, r = i % 324;
        int yy = r / 18, xx = r % 18;
        int gy = y0 + yy, gx = x0 + xx;
        float v = 0.0f;
        if (gy >= 0 && gy < 64 && gx >= 0 && gx < 64)
            v = xin[((size_t)b * CH + c) * NN + gy * 64 + gx];
        tile[c][r] = v;
    }
    __syncthreads();
    int py = tid >> 4, px = tid & 15;
    float acc[4];
    #pragma unroll
    for (int j = 0; j < 4; ++j) acc[j] = bsm[j];
    for (int i = 0; i < 32; ++i) {
        const float* tr = &tile[i][py * 18 + px];
        float v00 = tr[0],  v01 = tr[1],  v02 = tr[2];
        float v10 = tr[18], v11 = tr[19], v12 = tr[20];
        float v20 = tr[36], v21 = tr[37], v22 = tr[38];
        #pragma unroll
        for (int j = 0; j < 4; ++j) {
            const float* wj = &wsm[j * 288 + i * 9];
            acc[j] += v00 * wj[0] + v01 * wj[1] + v02 * wj[2]
                    + v10 * wj[3] + v11 * wj[4] + v12 * wj[5]
                    + v20 * wj[6] + v21 * wj[7] + v22 * wj[8];
        }
    }
    size_t base = (size_t)b * CH * NN + (size_t)(og * 4) * NN
                + (ty * 16 + py) * 64 + tx * 16 + px;
    #pragma unroll
    for (int j = 0; j < 4; ++j) {
        float r_ = fmaxf(acc[j], 0.0f);
        xout[base + j * NN] = r_;
        if (outx) outx[base + j * NN] = r_;
    }
}

// K6: final 3x3 conv 32->1 + b_out + corrected_map. channel-split 4x8, grid 256
__global__ void k6_convout(const float* __restrict__ xin, const float* __restrict__ w_out,
                           const float* __restrict__ b_out, const float* __restrict__ cmapf,
                           float* __restrict__ outp) {
    __shared__ float wsm[288];
    __shared__ float red[256];
    int tid = threadIdx.x;
    for (int i = tid; i < 288; i += 256) wsm[i] = w_out[i];
    int pxi = tid & 63, g = tid >> 6;
    int gid = blockIdx.x * 64 + pxi;   // B*N over 256 blocks
    int b = gid >> 12, hw = gid & 4095;
    int y = hw >> 6, x = hw & 63;
    __syncthreads();
    float acc = 0.0f;
    int c0 = g * 8;
    for (int i = c0; i < c0 + 8; ++i) {
        const float* xi = xin + ((size_t)b * CH + i) * NN;
        #pragma unroll
        for (int ky = 0; ky < 3; ++ky) {
            int gy = y + ky - 1;
            if (gy < 0 || gy > 63) continue;
            #pragma unroll
            for (int kx = 0; kx < 3; ++kx) {
                int gx = x + kx - 1;
                if (gx < 0 || gx > 63) continue;
                acc += xi[gy * 64 + gx] * wsm[i * 9 + ky * 3 + kx];
            }
        }
    }
    red[tid] = acc;
    __syncthreads();
    if (tid < 64) {
        float a = red[tid] + red[tid + 64] + red[tid + 128] + red[tid + 192]
                + b_out[0] + cmapf[gid];
        outp[OUT_O_OFF + gid] = a;
    }
}

extern "C" void kernel_launch(void* const* d_in, const int* in_sizes, int n_in,
                              void* d_out, int out_size, void* d_ws, size_t ws_size,
                              hipStream_t stream) {
    const float* f     = (const float*)d_in[0];
    const float* mapin = (const float*)d_in[1];
    const float* f_q   = (const float*)d_in[2];
    const float* f_k   = (const float*)d_in[3];
    const float* m_k   = (const float*)d_in[4];
    const float* wq    = (const float*)d_in[5];
    const float* wk    = (const float*)d_in[6];
    const float* w_in  = (const float*)d_in[7];
    const float* b_in  = (const float*)d_in[8];
    const float* w_mid = (const float*)d_in[9];
    const float* b_mid = (const float*)d_in[10];
    const float* w_out = (const float*)d_in[11];
    const float* b_out = (const float*)d_in[12];
    float* outp = (float*)d_out;   // reference outputs are float32
    float* ws = (float*)d_ws;

    float* PP    = ws + PP_OFF;
    float* Q4    = ws + Q4_OFF;
    float* K4    = ws + K4_OFF;
    float* CV    = ws + CV_OFF;
    float* CPMAX = ws + CPMAX_OFF;
    float* CPSUM = ws + CPSUM_OFF;
    float* RMAP  = ws + RMAP_OFF;
    float* CMAPF = ws + CMAPF_OFF;
    float* XA    = ws + XA_OFF;
    float* XB    = ws + XB_OFF;

    k0_posproj<<<1, 64, 0, stream>>>(wq, wk, PP);
    k1_qk<<<256, 256, 0, stream>>>(f_q, f_k, wq, wk, PP, Q4, K4);
    k2a_colstats<<<BB * NQCH * 16, 256, 0, stream>>>(Q4, K4, CPMAX, CPSUM);
    k2b_cmerge<<<64, 256, 0, stream>>>(CPMAX, CPSUM, m_k, CV);
    k3_top8<<<BB * 1024, 256, 0, stream>>>(Q4, K4, CV, mapin, RMAP, CMAPF, outp);
    k4_conv1<<<512, 256, 0, stream>>>(f, RMAP, w_in, b_in, XA);
    k5_conv3<<<512, 256, 0, stream>>>(XA, w_mid + 0 * 9216, b_mid + 0 * 32, XB, (float*)0);
    k5_conv3<<<512, 256, 0, stream>>>(XB, w_mid + 1 * 9216, b_mid + 1 * 32, XA, (float*)0);
    k5_conv3<<<512, 256, 0, stream>>>(XA, w_mid + 2 * 9216, b_mid + 2 * 32, XB, outp + OUT_X_OFF);
    k6_convout<<<256, 256, 0, stream>>>(XB, w_out, b_out, CMAPF, outp);
}

// Round 7
// 269.763 us; speedup vs baseline: 2.3074x; 1.0008x over previous
//
#include <hip/hip_runtime.h>
#include <hip/hip_bf16.h>
#include <math.h>

// Problem constants
#define BB 4
#define CIN 64
#define CH 32
#define HH 64
#define WW 64
#define NN 4096           // H*W
#define MCH 4
#define NQCH 32           // q-chunks for column stats (chunk = 128 queries)

// ws layout (floats). Total 1,229,824 floats = 4.69 MiB (proven size).
#define PP_OFF     0          // 1024
#define Q4_OFF     1024       // 65536
#define K4_OFF     66560      // 65536
#define CV_OFF     132096     // 16384
#define CPMAX_OFF  148480     // 524288 (dead after k2b)
#define CPSUM_OFF  672768     // 524288 (dead after k2b)
#define RMAP_OFF   148480     // 16384  (aliases CPMAX head)
#define CMAPF_OFF  164864     // 16384
#define XA_OFF     181248     // 524288
#define XB_OFF     705536     // 524288

// out layout (FLOAT32 elements): x | out | corrected_map
#define OUT_X_OFF   0
#define OUT_O_OFF   524288
#define OUT_CM_OFF  540672

__device__ __forceinline__ float bilin32(const float* src, int b, int y, int x) {
    float sy = 0.5f * y - 0.25f;
    float sx = 0.5f * x - 0.25f;
    float fy0 = floorf(sy), fx0 = floorf(sx);
    int y0 = (int)fy0, x0 = (int)fx0;
    float fy = sy - fy0, fx = sx - fx0;
    int y0c = min(max(y0, 0), 31), y1c = min(max(y0 + 1, 0), 31);
    int x0c = min(max(x0, 0), 31), x1c = min(max(x0 + 1, 0), 31);
    const float* p = src + b * 1024;
    float v00 = p[y0c * 32 + x0c], v01 = p[y0c * 32 + x1c];
    float v10 = p[y1c * 32 + x0c], v11 = p[y1c * 32 + x1c];
    float v0 = v00 + fx * (v01 - v00);
    float v1 = v10 + fx * (v11 - v10);
    return v0 + fy * (v1 - v0);
}

// K0: pos embedding projected through wq/wk, per coordinate (exact).
__global__ void k0_posproj(const float* __restrict__ wq, const float* __restrict__ wk,
                           float* __restrict__ pp) {
    int t = threadIdx.x;  // coordinate 0..63
    float coord = (float)(t + 1);
    float qy[4] = {0,0,0,0}, qx[4] = {0,0,0,0}, ky[4] = {0,0,0,0}, kx[4] = {0,0,0,0};
    for (int c = 0; c < 32; ++c) {
        float e = (2.0f * (float)(c / 2)) / 32.0f;
        float dim = powf(10000.0f, e);
        float ang = coord / dim;
        float pr = (c & 1) ? cosf(ang) : sinf(ang);
        #pragma unroll
        for (int m = 0; m < 4; ++m) {
            qy[m] += wq[m * 64 + c] * pr;
            qx[m] += wq[m * 64 + 32 + c] * pr;
            ky[m] += wk[m * 64 + c] * pr;
            kx[m] += wk[m * 64 + 32 + c] * pr;
        }
    }
    #pragma unroll
    for (int m = 0; m < 4; ++m) {
        pp[0 * 256 + m * 64 + t] = qy[m];
        pp[1 * 256 + m * 64 + t] = qx[m];
        pp[2 * 256 + m * 64 + t] = ky[m];
        pp[3 * 256 + m * 64 + t] = kx[m];
    }
}

// K1: Q/K projections, channel-split 4x16 + LDS reduce. grid = B*N/64 = 256
__global__ void k1_qk(const float* __restrict__ fq, const float* __restrict__ fk,
                      const float* __restrict__ wq, const float* __restrict__ wk,
                      const float* __restrict__ pp,
                      float* __restrict__ Q4, float* __restrict__ K4) {
    __shared__ float wqs[256], wks[256];
    __shared__ float red[256][9];
    int tid = threadIdx.x;
    wqs[tid] = wq[tid];
    wks[tid] = wk[tid];
    __syncthreads();
    int qi = tid & 63, g = tid >> 6;
    int gid = blockIdx.x * 64 + qi;
    int b = gid >> 12, hw = gid & 4095;
    const float* fqb = fq + (size_t)b * CIN * NN + hw;
    const float* fkb = fk + (size_t)b * CIN * NN + hw;
    float aq[4] = {0,0,0,0}, ak[4] = {0,0,0,0};
    int c0 = g * 16;
    #pragma unroll 4
    for (int c = c0; c < c0 + 16; ++c) {
        float vq = fqb[c * NN];
        float vk = fkb[c * NN];
        #pragma unroll
        for (int m = 0; m < 4; ++m) {
            aq[m] += wqs[m * 64 + c] * vq;
            ak[m] += wks[m * 64 + c] * vk;
        }
    }
    #pragma unroll
    for (int m = 0; m < 4; ++m) { red[tid][m] = aq[m]; red[tid][4 + m] = ak[m]; }
    __syncthreads();
    if (tid < 64) {
        int y = hw >> 6, x = hw & 63;
        float q4[4], k4[4];
        #pragma unroll
        for (int m = 0; m < 4; ++m) {
            q4[m] = red[tid][m] + red[tid + 64][m] + red[tid + 128][m] + red[tid + 192][m]
                  + pp[0 * 256 + m * 64 + y] + pp[1 * 256 + m * 64 + x];
            k4[m] = red[tid][4 + m] + red[tid + 64][4 + m] + red[tid + 128][4 + m] + red[tid + 192][4 + m]
                  + pp[2 * 256 + m * 64 + y] + pp[3 * 256 + m * 64 + x];
        }
        ((float4*)Q4)[gid] = make_float4(q4[0], q4[1], q4[2], q4[3]);
        ((float4*)K4)[gid] = make_float4(k4[0], k4[1], k4[2], k4[3]);
    }
}

// K2a: per-(b, q-chunk of 128) column max & sumexp, ONLINE single pass.
// grid = B*32*16 = 2048
__global__ void k2a_colstats(const float* __restrict__ Q4, const float* __restrict__ K4,
                             float* __restrict__ cpmax, float* __restrict__ cpsum) {
    __shared__ float4 Qs[128];
    int blk = blockIdx.x;
    int kblk = blk & 15;  blk >>= 4;
    int qch  = blk & 31;  blk >>= 5;
    int b    = blk;
    int tid = threadIdx.x;
    if (tid < 128)
        Qs[tid] = ((const float4*)Q4)[b * NN + qch * 128 + tid];
    __syncthreads();
    int k = kblk * 256 + tid;
    float4 kv = ((const float4*)K4)[b * NN + k];
    float m = -1e30f, sum = 0.0f;
    #pragma unroll 4
    for (int i = 0; i < 128; ++i) {
        float4 q = Qs[i];
        float s = q.x * kv.x + q.y * kv.y + q.z * kv.z + q.w * kv.w;
        if (s > m) { sum *= expf(m - s); m = s; }
        sum += expf(s - m);
    }
    cpmax[(b * NQCH + qch) * NN + k] = m;
    cpsum[(b * NQCH + qch) * NN + k] = sum;
}

// K2b: merge chunk stats -> c[b][k] = m_k_r - 1 - log(colsum) - colmax
__global__ void k2b_cmerge(const float* __restrict__ cpmax, const float* __restrict__ cpsum,
                           const float* __restrict__ m_k, float* __restrict__ cvals) {
    int gid = blockIdx.x * 256 + threadIdx.x;  // B*N
    int b = gid >> 12, k = gid & 4095;
    float M = -1e30f;
    #pragma unroll
    for (int j = 0; j < NQCH; ++j) M = fmaxf(M, cpmax[(b * NQCH + j) * NN + k]);
    float S = 0.0f;
    #pragma unroll
    for (int j = 0; j < NQCH; ++j)
        S += cpsum[(b * NQCH + j) * NN + k] * expf(cpmax[(b * NQCH + j) * NN + k] - M);
    float mk = bilin32(m_k, b, k >> 6, k & 63);
    cvals[gid] = mk - 1.0f - logf(S) - M;
}

// K3: wave-per-query top-8, threshold two-pass.
// Pass 1: cache all 64 s-values in regs + lane max. Threshold T = 8th largest
// of lane maxes (provably <= global v8 => safe filter). Pass 2: rare
// branchless min/max bubble insert of candidates >= T. Final 8-round
// argmax-pop merge (unchanged, verified).
__global__ __launch_bounds__(256, 4) void k3_top8(
        const float* __restrict__ Q4, const float* __restrict__ K4,
        const float* __restrict__ cvals, const float* __restrict__ mapin,
        float* __restrict__ rmap, float* __restrict__ cmapf,
        float* __restrict__ outp) {
    int blk = blockIdx.x;
    int b = blk >> 10;
    int qbase = (blk & 1023) * 4;
    int tid = threadIdx.x;
    int wave = tid >> 6;
    int lane = tid & 63;
    int q = qbase + wave;
    float4 qv = ((const float4*)Q4)[b * NN + q];
    const float4* Kb = (const float4*)K4 + b * NN;
    const float* cb = cvals + b * NN;

    // pass 1: compute + cache all 64 s-values (static indexing via full unroll)
    float sv[64];
    float mx = -1e30f;
    #pragma unroll
    for (int i = 0; i < 64; ++i) {
        int k = i * 64 + lane;
        float4 kv = Kb[k];
        float s = fmaf(qv.x, kv.x, fmaf(qv.y, kv.y,
                  fmaf(qv.z, kv.z, fmaf(qv.w, kv.w, cb[k]))));
        sv[i] = s;
        mx = fmaxf(mx, s);
    }

    // threshold: T = 8th largest of the 64 lane maxes
    float m = mx;
    float T = -1e30f;
    #pragma unroll
    for (int r = 0; r < 8; ++r) {
        float v = m;
        int ln = lane;
        #pragma unroll
        for (int off = 32; off >= 1; off >>= 1) {
            float ov = __shfl_xor(v, off);
            int ol = __shfl_xor(ln, off);
            if (ov > v || (ov == v && ol < ln)) { v = ov; ln = ol; }
        }
        T = v;
        if (lane == ln) m = -1e30f;
    }

    // pass 2: gather candidates >= T into per-lane ascending top-8 buffer
    float t0 = -1e30f, t1 = -1e30f, t2 = -1e30f, t3 = -1e30f;
    float t4 = -1e30f, t5 = -1e30f, t6 = -1e30f, t7 = -1e30f;
    #pragma unroll
    for (int i = 0; i < 64; ++i) {
        float s = sv[i];
        if (s >= T && s > t0) {
            float a = fmaxf(t0, s);
            t0 = fminf(a, t1); a = fmaxf(a, t1);
            t1 = fminf(a, t2); a = fmaxf(a, t2);
            t2 = fminf(a, t3); a = fmaxf(a, t3);
            t3 = fminf(a, t4); a = fmaxf(a, t4);
            t4 = fminf(a, t5); a = fmaxf(a, t5);
            t5 = fminf(a, t6); a = fmaxf(a, t6);
            t6 = fminf(a, t7); t7 = fmaxf(a, t7);
        }
    }

    // final merge: 8-round wave argmax-pop over candidate buffers
    float sm = 0.0f;
    #pragma unroll
    for (int r = 0; r < 8; ++r) {
        float v = t7;
        int ln = lane;
        #pragma unroll
        for (int off = 32; off >= 1; off >>= 1) {
            float ov = __shfl_xor(v, off);
            int ol = __shfl_xor(ln, off);
            if (ov > v || (ov == v && ol < ln)) { v = ov; ln = ol; }
        }
        sm += expf(v);
        if (lane == ln) {
            t7 = t6; t6 = t5; t5 = t4; t4 = t3; t3 = t2; t2 = t1; t1 = t0; t0 = -1e30f;
        }
    }

    if (lane == 0) {
        float cmv = sm * 0.125f;
        int gid = b * NN + q;
        float mr = bilin32(mapin, b, q >> 6, q & 63);
        float cm = cmv * mr + mr;
        float rm = 1.0f / (1.0f + expf(cm));
        rmap[gid] = rm;
        cmapf[gid] = cm;
        outp[OUT_CM_OFF + gid] = cm;
    }
}

// K4: x1 = conv1x1(rmap*f, w_in) + b_in. og-split 8 -> grid 512
__global__ void k4_conv1(const float* __restrict__ f, const float* __restrict__ rmap,
                         const float* __restrict__ w_in, const float* __restrict__ b_in,
                         float* __restrict__ xout) {
    __shared__ float ws_[1024];
    __shared__ float bs[32];
    int tid = threadIdx.x;
    for (int i = tid; i < 1024; i += 256) ws_[i] = w_in[i];
    if (tid < 32) bs[tid] = b_in[tid];
    __syncthreads();
    int gid = blockIdx.x * 256 + tid;      // b(2b) og(3b) hw(12b)
    int hw = gid & 4095;
    int og = (gid >> 12) & 7;
    int b  = gid >> 15;
    float rm = rmap[b * NN + hw];
    float acc[4];
    #pragma unroll
    for (int j = 0; j < 4; ++j) acc[j] = bs[og * 4 + j];
    const float* fb = f + (size_t)b * CH * NN + hw;
    for (int i = 0; i < 32; ++i) {
        float v = fb[i * NN] * rm;
        #pragma unroll
        for (int j = 0; j < 4; ++j) acc[j] += ws_[(og * 4 + j) * 32 + i] * v;
    }
    float* xo = xout + (size_t)b * CH * NN + (og * 4) * NN + hw;
    #pragma unroll
    for (int j = 0; j < 4; ++j) xo[j * NN] = acc[j];
}

// K5: 3x3 conv 32->32 (+bias, relu). og-split 8 -> grid = b*ty*tx*og = 512
__global__ void k5_conv3(const float* __restrict__ xin, const float* __restrict__ w,
                         const float* __restrict__ bias, float* __restrict__ xout,
                         float* __restrict__ outx) {
    __shared__ float tile[32][324];   // 18x18 per channel
    __shared__ float wsm[1152];       // 4 o x 32 i x 9
    __shared__ float bsm[4];
    int blk = blockIdx.x;
    int og = blk & 7;  blk >>= 3;
    int tx = blk & 3;  blk >>= 2;
    int ty = blk & 3;  blk >>= 2;
    int b  = blk;
    int tid = threadIdx.x;
    for (int i = tid; i < 1152; i += 256) wsm[i] = w[og * 1152 + i];
    if (tid < 4) bsm[tid] = bias[og * 4 + tid];
    int y0 = ty * 16 - 1, x0 = tx * 16 - 1;
    for (int i = tid; i < 32 * 324; i += 256) {
        int c = i / 324, r = i % 324;
        int yy = r / 18, xx = r % 18;
        int gy = y0 + yy, gx = x0 + xx;
        float v = 0.0f;
        if (gy >= 0 && gy < 64 && gx >= 0 && gx < 64)
            v = xin[((size_t)b * CH + c) * NN + gy * 64 + gx];
        tile[c][r] = v;
    }
    __syncthreads();
    int py = tid >> 4, px = tid & 15;
    float acc[4];
    #pragma unroll
    for (int j = 0; j < 4; ++j) acc[j] = bsm[j];
    for (int i = 0; i < 32; ++i) {
        const float* tr = &tile[i][py * 18 + px];
        float v00 = tr[0],  v01 = tr[1],  v02 = tr[2];
        float v10 = tr[18], v11 = tr[19], v12 = tr[20];
        float v20 = tr[36], v21 = tr[37], v22 = tr[38];
        #pragma unroll
        for (int j = 0; j < 4; ++j) {
            const float* wj = &wsm[j * 288 + i * 9];
            acc[j] += v00 * wj[0] + v01 * wj[1] + v02 * wj[2]
                    + v10 * wj[3] + v11 * wj[4] + v12 * wj[5]
                    + v20 * wj[6] + v21 * wj[7] + v22 * wj[8];
        }
    }
    size_t base = (size_t)b * CH * NN + (size_t)(og * 4) * NN
                + (ty * 16 + py) * 64 + tx * 16 + px;
    #pragma unroll
    for (int j = 0; j < 4; ++j) {
        float r_ = fmaxf(acc[j], 0.0f);
        xout[base + j * NN] = r_;
        if (outx) outx[base + j * NN] = r_;
    }
}

// K6: final 3x3 conv 32->1 + b_out + corrected_map. channel-split 4x8, grid 256
__global__ void k6_convout(const float* __restrict__ xin, const float* __restrict__ w_out,
                           const float* __restrict__ b_out, const float* __restrict__ cmapf,
                           float* __restrict__ outp) {
    __shared__ float wsm[288];
    __shared__ float red[256];
    int tid = threadIdx.x;
    for (int i = tid; i < 288; i += 256) wsm[i] = w_out[i];
    int pxi = tid & 63, g = tid >> 6;
    int gid = blockIdx.x * 64 + pxi;   // B*N over 256 blocks
    int b = gid >> 12, hw = gid & 4095;
    int y = hw >> 6, x = hw & 63;
    __syncthreads();
    float acc = 0.0f;
    int c0 = g * 8;
    for (int i = c0; i < c0 + 8; ++i) {
        const float* xi = xin + ((size_t)b * CH + i) * NN;
        #pragma unroll
        for (int ky = 0; ky < 3; ++ky) {
            int gy = y + ky - 1;
            if (gy < 0 || gy > 63) continue;
            #pragma unroll
            for (int kx = 0; kx < 3; ++kx) {
                int gx = x + kx - 1;
                if (gx < 0 || gx > 63) continue;
                acc += xi[gy * 64 + gx] * wsm[i * 9 + ky * 3 + kx];
            }
        }
    }
    red[tid] = acc;
    __syncthreads();
    if (tid < 64) {
        float a = red[tid] + red[tid + 64] + red[tid + 128] + red[tid + 192]
                + b_out[0] + cmapf[gid];
        outp[OUT_O_OFF + gid] = a;
    }
}

extern "C" void kernel_launch(void* const* d_in, const int* in_sizes, int n_in,
                              void* d_out, int out_size, void* d_ws, size_t ws_size,
                              hipStream_t stream) {
    const float* f     = (const float*)d_in[0];
    const float* mapin = (const float*)d_in[1];
    const float* f_q   = (const float*)d_in[2];
    const float* f_k   = (const float*)d_in[3];
    const float* m_k   = (const float*)d_in[4];
    const float* wq    = (const float*)d_in[5];
    const float* wk    = (const float*)d_in[6];
    const float* w_in  = (const float*)d_in[7];
    const float* b_in  = (const float*)d_in[8];
    const float* w_mid = (const float*)d_in[9];
    const float* b_mid = (const float*)d_in[10];
    const float* w_out = (const float*)d_in[11];
    const float* b_out = (const float*)d_in[12];
    float* outp = (float*)d_out;
    float* ws = (float*)d_ws;

    float* PP    = ws + PP_OFF;
    float* Q4    = ws + Q4_OFF;
    float* K4    = ws + K4_OFF;
    float* CV    = ws + CV_OFF;
    float* CPMAX = ws + CPMAX_OFF;
    float* CPSUM = ws + CPSUM_OFF;
    float* RMAP  = ws + RMAP_OFF;
    float* CMAPF = ws + CMAPF_OFF;
    float* XA    = ws + XA_OFF;
    float* XB    = ws + XB_OFF;

    k0_posproj<<<1, 64, 0, stream>>>(wq, wk, PP);
    k1_qk<<<256, 256, 0, stream>>>(f_q, f_k, wq, wk, PP, Q4, K4);
    k2a_colstats<<<BB * NQCH * 16, 256, 0, stream>>>(Q4, K4, CPMAX, CPSUM);
    k2b_cmerge<<<64, 256, 0, stream>>>(CPMAX, CPSUM, m_k, CV);
    k3_top8<<<BB * 1024, 256, 0, stream>>>(Q4, K4, CV, mapin, RMAP, CMAPF, outp);
    k4_conv1<<<512, 256, 0, stream>>>(f, RMAP, w_in, b_in, XA);
    k5_conv3<<<512, 256, 0, stream>>>(XA, w_mid + 0 * 9216, b_mid + 0 * 32, XB, (float*)0);
    k5_conv3<<<512, 256, 0, stream>>>(XB, w_mid + 1 * 9216, b_mid + 1 * 32, XA, (float*)0);
    k5_conv3<<<512, 256, 0, stream>>>(XA, w_mid + 2 * 9216, b_mid + 2 * 32, XB, outp + OUT_X_OFF);
    k6_convout<<<256, 256, 0, stream>>>(XB, w_out, b_out, CMAPF, outp);
}

// Round 8
// 224.835 us; speedup vs baseline: 2.7685x; 1.1998x over previous
//
#include <hip/hip_runtime.h>
#include <hip/hip_bf16.h>
#include <math.h>

// Problem constants
#define BB 4
#define CIN 64
#define CH 32
#define HH 64
#define WW 64
#define NN 4096           // H*W
#define MCH 4
#define NQCH 32           // q-chunks for column stats (chunk = 128 queries)
#define LOG2E 1.4426950408889634f

// ws layout (floats). Total 1,229,824 floats = 4.69 MiB (proven size).
#define PP_OFF     0          // 1024
#define Q4_OFF     1024       // 65536  (Q pre-scaled by LOG2E)
#define K4_OFF     66560      // 65536
#define CV_OFF     132096     // 16384  (c' in log2 domain)
#define CPMAX_OFF  148480     // (unused now)
#define CPSUM_OFF  672768     // 524288 (dead after k2b)
#define RMAP_OFF   148480     // 16384
#define CMAPF_OFF  164864     // 16384
#define XA_OFF     181248     // 524288
#define XB_OFF     705536     // 524288 (aliases CPSUM tail; CPSUM dead by then)

// out layout (FLOAT32 elements): x | out | corrected_map
#define OUT_X_OFF   0
#define OUT_O_OFF   524288
#define OUT_CM_OFF  540672

__device__ __forceinline__ float bilin32(const float* src, int b, int y, int x) {
    float sy = 0.5f * y - 0.25f;
    float sx = 0.5f * x - 0.25f;
    float fy0 = floorf(sy), fx0 = floorf(sx);
    int y0 = (int)fy0, x0 = (int)fx0;
    float fy = sy - fy0, fx = sx - fx0;
    int y0c = min(max(y0, 0), 31), y1c = min(max(y0 + 1, 0), 31);
    int x0c = min(max(x0, 0), 31), x1c = min(max(x0 + 1, 0), 31);
    const float* p = src + b * 1024;
    float v00 = p[y0c * 32 + x0c], v01 = p[y0c * 32 + x1c];
    float v10 = p[y1c * 32 + x0c], v11 = p[y1c * 32 + x1c];
    float v0 = v00 + fx * (v01 - v00);
    float v1 = v10 + fx * (v11 - v10);
    return v0 + fy * (v1 - v0);
}

// K0: pos embedding projected through wq/wk, per coordinate (exact).
__global__ void k0_posproj(const float* __restrict__ wq, const float* __restrict__ wk,
                           float* __restrict__ pp) {
    int t = threadIdx.x;  // coordinate 0..63
    float coord = (float)(t + 1);
    float qy[4] = {0,0,0,0}, qx[4] = {0,0,0,0}, ky[4] = {0,0,0,0}, kx[4] = {0,0,0,0};
    for (int c = 0; c < 32; ++c) {
        float e = (2.0f * (float)(c / 2)) / 32.0f;
        float dim = powf(10000.0f, e);
        float ang = coord / dim;
        float pr = (c & 1) ? cosf(ang) : sinf(ang);
        #pragma unroll
        for (int m = 0; m < 4; ++m) {
            qy[m] += wq[m * 64 + c] * pr;
            qx[m] += wq[m * 64 + 32 + c] * pr;
            ky[m] += wk[m * 64 + c] * pr;
            kx[m] += wk[m * 64 + 32 + c] * pr;
        }
    }
    #pragma unroll
    for (int m = 0; m < 4; ++m) {
        pp[0 * 256 + m * 64 + t] = qy[m];
        pp[1 * 256 + m * 64 + t] = qx[m];
        pp[2 * 256 + m * 64 + t] = ky[m];
        pp[3 * 256 + m * 64 + t] = kx[m];
    }
}

// K1: Q/K projections, channel-split 4x16 + LDS reduce. grid = B*N/64 = 256
// Q is written PRE-SCALED by LOG2E (exp2 domain); K natural.
__global__ void k1_qk(const float* __restrict__ fq, const float* __restrict__ fk,
                      const float* __restrict__ wq, const float* __restrict__ wk,
                      const float* __restrict__ pp,
                      float* __restrict__ Q4, float* __restrict__ K4) {
    __shared__ float wqs[256], wks[256];
    __shared__ float red[256][9];
    int tid = threadIdx.x;
    wqs[tid] = wq[tid];
    wks[tid] = wk[tid];
    __syncthreads();
    int qi = tid & 63, g = tid >> 6;
    int gid = blockIdx.x * 64 + qi;
    int b = gid >> 12, hw = gid & 4095;
    const float* fqb = fq + (size_t)b * CIN * NN + hw;
    const float* fkb = fk + (size_t)b * CIN * NN + hw;
    float aq[4] = {0,0,0,0}, ak[4] = {0,0,0,0};
    int c0 = g * 16;
    #pragma unroll 4
    for (int c = c0; c < c0 + 16; ++c) {
        float vq = fqb[c * NN];
        float vk = fkb[c * NN];
        #pragma unroll
        for (int m = 0; m < 4; ++m) {
            aq[m] += wqs[m * 64 + c] * vq;
            ak[m] += wks[m * 64 + c] * vk;
        }
    }
    #pragma unroll
    for (int m = 0; m < 4; ++m) { red[tid][m] = aq[m]; red[tid][4 + m] = ak[m]; }
    __syncthreads();
    if (tid < 64) {
        int y = hw >> 6, x = hw & 63;
        float q4[4], k4[4];
        #pragma unroll
        for (int m = 0; m < 4; ++m) {
            q4[m] = LOG2E * (red[tid][m] + red[tid + 64][m] + red[tid + 128][m] + red[tid + 192][m]
                  + pp[0 * 256 + m * 64 + y] + pp[1 * 256 + m * 64 + x]);
            k4[m] = red[tid][4 + m] + red[tid + 64][4 + m] + red[tid + 128][4 + m] + red[tid + 192][4 + m]
                  + pp[2 * 256 + m * 64 + y] + pp[3 * 256 + m * 64 + x];
        }
        ((float4*)Q4)[gid] = make_float4(q4[0], q4[1], q4[2], q4[3]);
        ((float4*)K4)[gid] = make_float4(k4[0], k4[1], k4[2], k4[3]);
    }
}

// K2a: per-(b, q-chunk of 128) column sum of exp(sim) = 2^(q'.k), direct (no max).
// 2 keys/thread. grid = B*NQCH*8 = 1024, block 256.
__global__ void k2a_colstats(const float* __restrict__ Q4, const float* __restrict__ K4,
                             float* __restrict__ cpsum) {
    __shared__ float4 Qs[128];
    int blk = blockIdx.x;
    int kblk = blk & 7;   blk >>= 3;
    int qch  = blk & 31;  blk >>= 5;
    int b    = blk;
    int tid = threadIdx.x;
    if (tid < 128)
        Qs[tid] = ((const float4*)Q4)[b * NN + qch * 128 + tid];
    __syncthreads();
    int k0 = kblk * 512 + tid;
    float4 kva = ((const float4*)K4)[b * NN + k0];
    float4 kvb = ((const float4*)K4)[b * NN + k0 + 256];
    float sa = 0.0f, sb = 0.0f;
    #pragma unroll 8
    for (int i = 0; i < 128; ++i) {
        float4 q = Qs[i];
        float da = fmaf(q.x, kva.x, fmaf(q.y, kva.y, fmaf(q.z, kva.z, q.w * kva.w)));
        float db = fmaf(q.x, kvb.x, fmaf(q.y, kvb.y, fmaf(q.z, kvb.z, q.w * kvb.w)));
        sa += exp2f(da);
        sb += exp2f(db);
    }
    cpsum[(b * NQCH + qch) * NN + k0] = sa;
    cpsum[(b * NQCH + qch) * NN + k0 + 256] = sb;
}

// K2b: merge chunk sums -> c'[b][k] = LOG2E*(m_k_r - 1) - log2(colsum)
__global__ void k2b_cmerge(const float* __restrict__ cpsum,
                           const float* __restrict__ m_k, float* __restrict__ cvals) {
    int gid = blockIdx.x * 256 + threadIdx.x;  // B*N
    int b = gid >> 12, k = gid & 4095;
    float S = 0.0f;
    #pragma unroll
    for (int j = 0; j < NQCH; ++j) S += cpsum[(b * NQCH + j) * NN + k];
    float mk = bilin32(m_k, b, k >> 6, k & 63);
    cvals[gid] = LOG2E * (mk - 1.0f) - log2f(S);
}

// K3: wave-per-query top-8, threshold two-pass (log2 domain).
// Threshold T = min over 8 group-maxima (6 shuffles; provably <= v8).
__global__ __launch_bounds__(256, 4) void k3_top8(
        const float* __restrict__ Q4, const float* __restrict__ K4,
        const float* __restrict__ cvals, const float* __restrict__ mapin,
        float* __restrict__ rmap, float* __restrict__ cmapf,
        float* __restrict__ outp) {
    int blk = blockIdx.x;
    int b = blk >> 10;
    int qbase = (blk & 1023) * 4;
    int tid = threadIdx.x;
    int wave = tid >> 6;
    int lane = tid & 63;
    int q = qbase + wave;
    float4 qv = ((const float4*)Q4)[b * NN + q];
    const float4* Kb = (const float4*)K4 + b * NN;
    const float* cb = cvals + b * NN;

    // pass 1: compute + cache all 64 s'-values; lane max
    float sv[64];
    float mx = -1e30f;
    #pragma unroll
    for (int i = 0; i < 64; ++i) {
        int k = i * 64 + lane;
        float4 kv = Kb[k];
        float s = fmaf(qv.x, kv.x, fmaf(qv.y, kv.y,
                  fmaf(qv.z, kv.z, fmaf(qv.w, kv.w, cb[k]))));
        sv[i] = s;
        mx = fmaxf(mx, s);
    }

    // threshold: T = min over the 8 group-maxima (groups of 8 lanes)
    float gmax = mx;
    gmax = fmaxf(gmax, __shfl_xor(gmax, 1));
    gmax = fmaxf(gmax, __shfl_xor(gmax, 2));
    gmax = fmaxf(gmax, __shfl_xor(gmax, 4));
    float T = gmax;
    T = fminf(T, __shfl_xor(T, 8));
    T = fminf(T, __shfl_xor(T, 16));
    T = fminf(T, __shfl_xor(T, 32));

    // pass 2: gather candidates >= T into per-lane ascending top-8 buffer
    float t0 = -1e30f, t1 = -1e30f, t2 = -1e30f, t3 = -1e30f;
    float t4 = -1e30f, t5 = -1e30f, t6 = -1e30f, t7 = -1e30f;
    #pragma unroll
    for (int i = 0; i < 64; ++i) {
        float s = sv[i];
        if (s >= T && s > t0) {
            float a = fmaxf(t0, s);
            t0 = fminf(a, t1); a = fmaxf(a, t1);
            t1 = fminf(a, t2); a = fmaxf(a, t2);
            t2 = fminf(a, t3); a = fmaxf(a, t3);
            t3 = fminf(a, t4); a = fmaxf(a, t4);
            t4 = fminf(a, t5); a = fmaxf(a, t5);
            t5 = fminf(a, t6); a = fmaxf(a, t6);
            t6 = fminf(a, t7); t7 = fmaxf(a, t7);
        }
    }

    // final merge: 8-round wave argmax-pop over candidate buffers
    float sm = 0.0f;
    #pragma unroll
    for (int r = 0; r < 8; ++r) {
        float v = t7;
        int ln = lane;
        #pragma unroll
        for (int off = 32; off >= 1; off >>= 1) {
            float ov = __shfl_xor(v, off);
            int ol = __shfl_xor(ln, off);
            if (ov > v || (ov == v && ol < ln)) { v = ov; ln = ol; }
        }
        sm += exp2f(v);
        if (lane == ln) {
            t7 = t6; t6 = t5; t5 = t4; t4 = t3; t3 = t2; t2 = t1; t1 = t0; t0 = -1e30f;
        }
    }

    if (lane == 0) {
        float cmv = sm * 0.125f;
        int gid = b * NN + q;
        float mr = bilin32(mapin, b, q >> 6, q & 63);
        float cm = cmv * mr + mr;
        float rm = 1.0f / (1.0f + __expf(cm));
        rmap[gid] = rm;
        cmapf[gid] = cm;
        outp[OUT_CM_OFF + gid] = cm;
    }
}

// K4: x1 = conv1x1(rmap*f, w_in) + b_in. og-split 8 -> grid 512
__global__ void k4_conv1(const float* __restrict__ f, const float* __restrict__ rmap,
                         const float* __restrict__ w_in, const float* __restrict__ b_in,
                         float* __restrict__ xout) {
    __shared__ float ws_[1024];
    __shared__ float bs[32];
    int tid = threadIdx.x;
    for (int i = tid; i < 1024; i += 256) ws_[i] = w_in[i];
    if (tid < 32) bs[tid] = b_in[tid];
    __syncthreads();
    int gid = blockIdx.x * 256 + tid;      // b(2b) og(3b) hw(12b)
    int hw = gid & 4095;
    int og = (gid >> 12) & 7;
    int b  = gid >> 15;
    float rm = rmap[b * NN + hw];
    float acc[4];
    #pragma unroll
    for (int j = 0; j < 4; ++j) acc[j] = bs[og * 4 + j];
    const float* fb = f + (size_t)b * CH * NN + hw;
    for (int i = 0; i < 32; ++i) {
        float v = fb[i * NN] * rm;
        #pragma unroll
        for (int j = 0; j < 4; ++j) acc[j] += ws_[(og * 4 + j) * 32 + i] * v;
    }
    float* xo = xout + (size_t)b * CH * NN + (og * 4) * NN + hw;
    #pragma unroll
    for (int j = 0; j < 4; ++j) xo[j * NN] = acc[j];
}

// K5: 3x3 conv 32->32 (+bias, relu). og-split 8 -> grid = b*ty*tx*og = 512
__global__ void k5_conv3(const float* __restrict__ xin, const float* __restrict__ w,
                         const float* __restrict__ bias, float* __restrict__ xout,
                         float* __restrict__ outx) {
    __shared__ float tile[32][324];   // 18x18 per channel
    __shared__ float wsm[1152];       // 4 o x 32 i x 9
    __shared__ float bsm[4];
    int blk = blockIdx.x;
    int og = blk & 7;  blk >>= 3;
    int tx = blk & 3;  blk >>= 2;
    int ty = blk & 3;  blk >>= 2;
    int b  = blk;
    int tid = threadIdx.x;
    for (int i = tid; i < 1152; i += 256) wsm[i] = w[og * 1152 + i];
    if (tid < 4) bsm[tid] = bias[og * 4 + tid];
    int y0 = ty * 16 - 1, x0 = tx * 16 - 1;
    for (int i = tid; i < 32 * 324; i += 256) {
        int c = i / 324, r = i % 324;
        int yy = r / 18, xx = r % 18;
        int gy = y0 + yy, gx = x0 + xx;
        float v = 0.0f;
        if (gy >= 0 && gy < 64 && gx >= 0 && gx < 64)
            v = xin[((size_t)b * CH + c) * NN + gy * 64 + gx];
        tile[c][r] = v;
    }
    __syncthreads();
    int py = tid >> 4, px = tid & 15;
    float acc[4];
    #pragma unroll
    for (int j = 0; j < 4; ++j) acc[j] = bsm[j];
    for (int i = 0; i < 32; ++i) {
        const float* tr = &tile[i][py * 18 + px];
        float v00 = tr[0],  v01 = tr[1],  v02 = tr[2];
        float v10 = tr[18], v11 = tr[19], v12 = tr[20];
        float v20 = tr[36], v21 = tr[37], v22 = tr[38];
        #pragma unroll
        for (int j = 0; j < 4; ++j) {
            const float* wj = &wsm[j * 288 + i * 9];
            acc[j] += v00 * wj[0] + v01 * wj[1] + v02 * wj[2]
                    + v10 * wj[3] + v11 * wj[4] + v12 * wj[5]
                    + v20 * wj[6] + v21 * wj[7] + v22 * wj[8];
        }
    }
    size_t base = (size_t)b * CH * NN + (size_t)(og * 4) * NN
                + (ty * 16 + py) * 64 + tx * 16 + px;
    #pragma unroll
    for (int j = 0; j < 4; ++j) {
        float r_ = fmaxf(acc[j], 0.0f);
        xout[base + j * NN] = r_;
        if (outx) outx[base + j * NN] = r_;
    }
}

// K6: final 3x3 conv 32->1 + b_out + corrected_map. channel-split 4x8, grid 256
__global__ void k6_convout(const float* __restrict__ xin, const float* __restrict__ w_out,
                           const float* __restrict__ b_out, const float* __restrict__ cmapf,
                           float* __restrict__ outp) {
    __shared__ float wsm[288];
    __shared__ float red[256];
    int tid = threadIdx.x;
    for (int i = tid; i < 288; i += 256) wsm[i] = w_out[i];
    int pxi = tid & 63, g = tid >> 6;
    int gid = blockIdx.x * 64 + pxi;   // B*N over 256 blocks
    int b = gid >> 12, hw = gid & 4095;
    int y = hw >> 6, x = hw & 63;
    __syncthreads();
    float acc = 0.0f;
    int c0 = g * 8;
    for (int i = c0; i < c0 + 8; ++i) {
        const float* xi = xin + ((size_t)b * CH + i) * NN;
        #pragma unroll
        for (int ky = 0; ky < 3; ++ky) {
            int gy = y + ky - 1;
            if (gy < 0 || gy > 63) continue;
            #pragma unroll
            for (int kx = 0; kx < 3; ++kx) {
                int gx = x + kx - 1;
                if (gx < 0 || gx > 63) continue;
                acc += xi[gy * 64 + gx] * wsm[i * 9 + ky * 3 + kx];
            }
        }
    }
    red[tid] = acc;
    __syncthreads();
    if (tid < 64) {
        float a = red[tid] + red[tid + 64] + red[tid + 128] + red[tid + 192]
                + b_out[0] + cmapf[gid];
        outp[OUT_O_OFF + gid] = a;
    }
}

extern "C" void kernel_launch(void* const* d_in, const int* in_sizes, int n_in,
                              void* d_out, int out_size, void* d_ws, size_t ws_size,
                              hipStream_t stream) {
    const float* f     = (const float*)d_in[0];
    const float* mapin = (const float*)d_in[1];
    const float* f_q   = (const float*)d_in[2];
    const float* f_k   = (const float*)d_in[3];
    const float* m_k   = (const float*)d_in[4];
    const float* wq    = (const float*)d_in[5];
    const float* wk    = (const float*)d_in[6];
    const float* w_in  = (const float*)d_in[7];
    const float* b_in  = (const float*)d_in[8];
    const float* w_mid = (const float*)d_in[9];
    const float* b_mid = (const float*)d_in[10];
    const float* w_out = (const float*)d_in[11];
    const float* b_out = (const float*)d_in[12];
    float* outp = (float*)d_out;
    float* ws = (float*)d_ws;

    float* PP    = ws + PP_OFF;
    float* Q4    = ws + Q4_OFF;
    float* K4    = ws + K4_OFF;
    float* CV    = ws + CV_OFF;
    float* CPSUM = ws + CPSUM_OFF;
    float* RMAP  = ws + RMAP_OFF;
    float* CMAPF = ws + CMAPF_OFF;
    float* XA    = ws + XA_OFF;
    float* XB    = ws + XB_OFF;

    k0_posproj<<<1, 64, 0, stream>>>(wq, wk, PP);
    k1_qk<<<256, 256, 0, stream>>>(f_q, f_k, wq, wk, PP, Q4, K4);
    k2a_colstats<<<BB * NQCH * 8, 256, 0, stream>>>(Q4, K4, CPSUM);
    k2b_cmerge<<<64, 256, 0, stream>>>(CPSUM, m_k, CV);
    k3_top8<<<BB * 1024, 256, 0, stream>>>(Q4, K4, CV, mapin, RMAP, CMAPF, outp);
    k4_conv1<<<512, 256, 0, stream>>>(f, RMAP, w_in, b_in, XA);
    k5_conv3<<<512, 256, 0, stream>>>(XA, w_mid + 0 * 9216, b_mid + 0 * 32, XB, (float*)0);
    k5_conv3<<<512, 256, 0, stream>>>(XB, w_mid + 1 * 9216, b_mid + 1 * 32, XA, (float*)0);
    k5_conv3<<<512, 256, 0, stream>>>(XA, w_mid + 2 * 9216, b_mid + 2 * 32, XB, outp + OUT_X_OFF);
    k6_convout<<<256, 256, 0, stream>>>(XB, w_out, b_out, CMAPF, outp);
}